// Round 2
// baseline (10339.143 us; speedup 1.0000x reference)
//
#include <hip/hip_runtime.h>
#include <math.h>

#define L_ 4
#define D_ 256
#define H_ 8
#define DH_ 256
#define INNER_ 2048
#define M_ 1024
#define B_ 8
#define N_ 1024
#define R_ (B_ * N_)          // 8192 rows
#define QKV_STRIDE_ 6144      // 3*INNER

constexpr float EPS_ = 1e-5f;
constexpr float SCALE_ = 0.0625f;  // 256^-0.5

__device__ __forceinline__ float gelu_f(float x) {
    return 0.5f * x * (1.0f + erff(x * 0.70710678118654752f));
}

// ---------------------------------------------------------------------------
// LayerNorm: one block per row of 256, 256 threads (one per column)
// ---------------------------------------------------------------------------
__global__ __launch_bounds__(256)
void ln_kernel(const float* __restrict__ x, const float* __restrict__ g,
               const float* __restrict__ b, float* __restrict__ out) {
    const int row = blockIdx.x;
    const int t = threadIdx.x;
    const int wave = t >> 6, lane = t & 63;
    __shared__ float red[8];

    const float v = x[(size_t)row * D_ + t];

    float s = v;
    #pragma unroll
    for (int o = 32; o; o >>= 1) s += __shfl_down(s, o);
    if (lane == 0) red[wave] = s;
    __syncthreads();
    const float mean = (red[0] + red[1] + red[2] + red[3]) * (1.0f / 256.0f);

    const float d = v - mean;
    float s2 = d * d;
    #pragma unroll
    for (int o = 32; o; o >>= 1) s2 += __shfl_down(s2, o);
    if (lane == 0) red[4 + wave] = s2;   // disjoint slots: no race with reads of [0..3]
    __syncthreads();
    const float var = (red[4] + red[5] + red[6] + red[7]) * (1.0f / 256.0f);

    out[(size_t)row * D_ + t] = d * rsqrtf(var + EPS_) * g[t] + b[t];
}

// ---------------------------------------------------------------------------
// SGEMM: C[rows x Nc] = A[rows x K] @ W[K x Nc] (+bias) (+GELU) (+residual)
// A has row stride lda (>= K) so we can read the Q-slot of the qkv buffer.
// BM=128, BK=16, 256 threads. Micro-tile TM x TN per thread.
// ---------------------------------------------------------------------------
template <int BM, int BN, int BK, int TM, int TN, bool BIAS, bool RES, bool GELU>
__global__ __launch_bounds__(256)
void gemm_kernel(const float* __restrict__ A, const float* __restrict__ W,
                 const float* __restrict__ bias, float* __restrict__ C,
                 int K, int lda, int Nc) {
    static_assert((BM / TM) * (BN / TN) == 256, "256 threads");
    __shared__ float As[BK][BM];
    __shared__ float Bs[BK][BN];

    const int t = threadIdx.x;
    const int tx = t % 16;
    const int ty = t / 16;
    const int row0 = blockIdx.y * BM;
    const int col0 = blockIdx.x * BN;

    float acc[TM][TN] = {};

    for (int k0 = 0; k0 < K; k0 += BK) {
        // stage A tile (BM x BK), float4 along K, store transposed
        #pragma unroll
        for (int i = t * 4; i < BM * BK; i += 1024) {
            const int r = i / BK, kk = i % BK;
            const float4 av = *reinterpret_cast<const float4*>(
                &A[(size_t)(row0 + r) * lda + k0 + kk]);
            As[kk + 0][r] = av.x; As[kk + 1][r] = av.y;
            As[kk + 2][r] = av.z; As[kk + 3][r] = av.w;
        }
        // stage W tile (BK x BN), float4 along N
        #pragma unroll
        for (int i = t * 4; i < BK * BN; i += 1024) {
            const int kk = i / BN, n = i % BN;
            *reinterpret_cast<float4*>(&Bs[kk][n]) =
                *reinterpret_cast<const float4*>(&W[(size_t)(k0 + kk) * Nc + col0 + n]);
        }
        __syncthreads();

        #pragma unroll
        for (int kk = 0; kk < BK; ++kk) {
            float a[TM], bfr[TN];
            #pragma unroll
            for (int i = 0; i < TM; ++i) a[i] = As[kk][ty + i * 16];
            #pragma unroll
            for (int jj = 0; jj < TN / 4; ++jj) {
                const float4 bv = *reinterpret_cast<const float4*>(&Bs[kk][tx * 4 + jj * 64]);
                bfr[jj * 4 + 0] = bv.x; bfr[jj * 4 + 1] = bv.y;
                bfr[jj * 4 + 2] = bv.z; bfr[jj * 4 + 3] = bv.w;
            }
            #pragma unroll
            for (int i = 0; i < TM; ++i)
                #pragma unroll
                for (int j = 0; j < TN; ++j) acc[i][j] += a[i] * bfr[j];
        }
        __syncthreads();
    }

    // epilogue
    #pragma unroll
    for (int i = 0; i < TM; ++i) {
        const size_t r = row0 + ty + i * 16;
        #pragma unroll
        for (int jj = 0; jj < TN / 4; ++jj) {
            const int c = col0 + tx * 4 + jj * 64;
            float4 v;
            v.x = acc[i][jj * 4 + 0]; v.y = acc[i][jj * 4 + 1];
            v.z = acc[i][jj * 4 + 2]; v.w = acc[i][jj * 4 + 3];
            if constexpr (BIAS) {
                v.x += bias[c]; v.y += bias[c + 1]; v.z += bias[c + 2]; v.w += bias[c + 3];
            }
            if constexpr (GELU) {
                v.x = gelu_f(v.x); v.y = gelu_f(v.y); v.z = gelu_f(v.z); v.w = gelu_f(v.w);
            }
            float* cp = &C[r * Nc + c];
            if constexpr (RES) {
                const float4 old = *reinterpret_cast<const float4*>(cp);
                v.x += old.x; v.y += old.y; v.z += old.z; v.w += old.w;
            }
            *reinterpret_cast<float4*>(cp) = v;
        }
    }
}

// ---------------------------------------------------------------------------
// Flash attention (fp32), IN-PLACE: output overwrites the Q slot of qkv.
// Safe: each block consumes its Q tile into LDS before the KV loop and writes
// the same (rows x head-cols) region only at the very end; blocks touch
// disjoint regions.  qkv is row-major [rows x 6144], batch-local.
// grid (N/64, local_batches*H), 256 threads.
// ---------------------------------------------------------------------------
__global__ __launch_bounds__(256)
void attn_kernel(float* __restrict__ qkv) {
    constexpr int ST = 260;  // float4-aligned padded stride
    __shared__ float Qs[64][ST];
    __shared__ float Ks[32][ST];
    __shared__ float Vs[32][ST];
    __shared__ float Ps[64][33];

    const int t = threadIdx.x;
    const int tx = t & 15, ty = t >> 4;
    const int bh = blockIdx.y;
    const int b = bh >> 3, hh = bh & 7;   // b is chunk-local
    const int q0 = blockIdx.x << 6;       // *64

    const size_t base = (size_t)b * N_ * QKV_STRIDE_;
    float* Qg = qkv + base + hh * DH_;
    const float* Kg = qkv + base + INNER_ + hh * DH_;
    const float* Vg = qkv + base + 2 * INNER_ + hh * DH_;

    // load Q tile: 64 x 256 = 4096 float4
    #pragma unroll
    for (int i = 0; i < 16; ++i) {
        const int idx = (i * 256 + t) * 4;
        const int r = idx >> 8, c = idx & 255;
        *reinterpret_cast<float4*>(&Qs[r][c]) =
            *reinterpret_cast<const float4*>(&Qg[(size_t)(q0 + r) * QKV_STRIDE_ + c]);
    }

    float m[4] = {-INFINITY, -INFINITY, -INFINITY, -INFINITY};
    float l[4] = {};
    float o[4][4][4] = {};

    for (int kt = 0; kt < N_ / 32; ++kt) {
        const int k0 = kt * 32;
        #pragma unroll
        for (int i = 0; i < 8; ++i) {
            const int idx = (i * 256 + t) * 4;
            const int r = idx >> 8, c = idx & 255;
            *reinterpret_cast<float4*>(&Ks[r][c]) =
                *reinterpret_cast<const float4*>(&Kg[(size_t)(k0 + r) * QKV_STRIDE_ + c]);
            *reinterpret_cast<float4*>(&Vs[r][c]) =
                *reinterpret_cast<const float4*>(&Vg[(size_t)(k0 + r) * QKV_STRIDE_ + c]);
        }
        __syncthreads();

        // S = Q @ K^T * SCALE  (4 rows x 2 cols per thread)
        float s[4][2] = {};
        #pragma unroll 4
        for (int kk = 0; kk < 256; kk += 4) {
            const float4 k0v = *reinterpret_cast<const float4*>(&Ks[tx][kk]);
            const float4 k1v = *reinterpret_cast<const float4*>(&Ks[tx + 16][kk]);
            #pragma unroll
            for (int i = 0; i < 4; ++i) {
                const float4 qv = *reinterpret_cast<const float4*>(&Qs[ty + 16 * i][kk]);
                s[i][0] += qv.x * k0v.x + qv.y * k0v.y + qv.z * k0v.z + qv.w * k0v.w;
                s[i][1] += qv.x * k1v.x + qv.y * k1v.y + qv.z * k1v.z + qv.w * k1v.w;
            }
        }

        // online softmax
        float mx[4], al[4], ps[4];
        #pragma unroll
        for (int i = 0; i < 4; ++i) {
            s[i][0] *= SCALE_; s[i][1] *= SCALE_;
            mx[i] = fmaxf(s[i][0], s[i][1]);
        }
        #pragma unroll
        for (int off = 1; off < 16; off <<= 1) {
            #pragma unroll
            for (int i = 0; i < 4; ++i) mx[i] = fmaxf(mx[i], __shfl_xor(mx[i], off, 16));
        }
        #pragma unroll
        for (int i = 0; i < 4; ++i) {
            const float nm = fmaxf(m[i], mx[i]);
            al[i] = __expf(m[i] - nm);
            m[i] = nm;
            s[i][0] = __expf(s[i][0] - nm);
            s[i][1] = __expf(s[i][1] - nm);
            ps[i] = s[i][0] + s[i][1];
        }
        #pragma unroll
        for (int off = 1; off < 16; off <<= 1) {
            #pragma unroll
            for (int i = 0; i < 4; ++i) ps[i] += __shfl_xor(ps[i], off, 16);
        }
        #pragma unroll
        for (int i = 0; i < 4; ++i) {
            l[i] = l[i] * al[i] + ps[i];
            Ps[ty + 16 * i][tx] = s[i][0];
            Ps[ty + 16 * i][tx + 16] = s[i][1];
            #pragma unroll
            for (int j = 0; j < 4; ++j)
                #pragma unroll
                for (int c = 0; c < 4; ++c) o[i][j][c] *= al[i];
        }
        __syncthreads();

        // PV: out[4 rows][16 cols] += P[4 rows][kc] * V[kc][16 cols]
        #pragma unroll 2
        for (int kc = 0; kc < 32; ++kc) {
            float p[4];
            #pragma unroll
            for (int i = 0; i < 4; ++i) p[i] = Ps[ty + 16 * i][kc];
            #pragma unroll
            for (int j = 0; j < 4; ++j) {
                const float4 vv = *reinterpret_cast<const float4*>(&Vs[kc][tx * 4 + j * 64]);
                #pragma unroll
                for (int i = 0; i < 4; ++i) {
                    o[i][j][0] += p[i] * vv.x;
                    o[i][j][1] += p[i] * vv.y;
                    o[i][j][2] += p[i] * vv.z;
                    o[i][j][3] += p[i] * vv.w;
                }
            }
        }
        __syncthreads();
    }

    // normalize and write back into the Q slot (consumed above, disjoint per block)
    #pragma unroll
    for (int i = 0; i < 4; ++i) {
        const float inv = 1.0f / l[i];
        const size_t row = (size_t)(q0 + ty + 16 * i);
        #pragma unroll
        for (int j = 0; j < 4; ++j) {
            float4 w;
            w.x = o[i][j][0] * inv; w.y = o[i][j][1] * inv;
            w.z = o[i][j][2] * inv; w.w = o[i][j][3] * inv;
            *reinterpret_cast<float4*>(&Qg[row * QKV_STRIDE_ + tx * 4 + j * 64]) = w;
        }
    }
}

// ---------------------------------------------------------------------------
extern "C" void kernel_launch(void* const* d_in, const int* in_sizes, int n_in,
                              void* d_out, int out_size, void* d_ws, size_t ws_size,
                              hipStream_t stream) {
    (void)in_sizes; (void)n_in; (void)out_size;

    const float* inputs = (const float*)d_in[0];
    const float* ln1_g  = (const float*)d_in[1];
    const float* ln1_b  = (const float*)d_in[2];
    const float* w_qkv  = (const float*)d_in[3];
    const float* w_proj = (const float*)d_in[4];
    const float* b_proj = (const float*)d_in[5];
    const float* ln2_g  = (const float*)d_in[6];
    const float* ln2_b  = (const float*)d_in[7];
    const float* w1     = (const float*)d_in[8];
    const float* b1     = (const float*)d_in[9];
    const float* w2     = (const float*)d_in[10];
    const float* b2     = (const float*)d_in[11];

    float* x = (float*)d_out;                 // running residual [R x D]
    float* h = (float*)d_ws;                  // LN output        [R x D]
    float* qc = h + (size_t)R_ * D_;          // qkv chunk buffer [R/nchunks x 6144]

    // Pick the smallest chunking whose footprint fits ws_size.
    // need = R*D*4 (h) + (R/nchunks)*6144*4 (qkv chunk); MLP hidden aliases qc.
    const size_t hbytes = (size_t)R_ * D_ * sizeof(float);
    int nchunks = 1;
    while (nchunks < 8 &&
           hbytes + ((size_t)R_ / nchunks) * QKV_STRIDE_ * sizeof(float) > ws_size)
        nchunks *= 2;
    const int CB = B_ / nchunks;   // batches per chunk
    const int CR = R_ / nchunks;   // rows per chunk

    hipMemcpyAsync(x, inputs, (size_t)R_ * D_ * sizeof(float),
                   hipMemcpyDeviceToDevice, stream);

    for (int l = 0; l < L_; ++l) {
        // --- attention sub-block ---
        ln_kernel<<<R_, 256, 0, stream>>>(x, ln1_g + l * D_, ln1_b + l * D_, h);

        for (int c = 0; c < nchunks; ++c) {
            const size_t r0 = (size_t)c * CR;
            gemm_kernel<128, 128, 16, 8, 8, false, false, false>
                <<<dim3(QKV_STRIDE_ / 128, CR / 128), 256, 0, stream>>>(
                    h + r0 * D_, w_qkv + (size_t)l * D_ * QKV_STRIDE_, nullptr, qc,
                    D_, D_, QKV_STRIDE_);

            attn_kernel<<<dim3(N_ / 64, CB * H_), 256, 0, stream>>>(qc);

            gemm_kernel<128, 64, 16, 8, 4, true, true, false>
                <<<dim3(D_ / 64, CR / 128), 256, 0, stream>>>(
                    qc, w_proj + (size_t)l * INNER_ * D_, b_proj + l * D_, x + r0 * D_,
                    INNER_, QKV_STRIDE_, D_);
        }

        // --- MLP sub-block ---
        ln_kernel<<<R_, 256, 0, stream>>>(x, ln2_g + l * D_, ln2_b + l * D_, h);

        for (int c = 0; c < nchunks; ++c) {
            const size_t r0 = (size_t)c * CR;
            float* hid = qc;  // [CR x M] aliases qkv chunk buffer
            gemm_kernel<128, 128, 16, 8, 8, true, false, true>
                <<<dim3(M_ / 128, CR / 128), 256, 0, stream>>>(
                    h + r0 * D_, w1 + (size_t)l * D_ * M_, b1 + l * M_, hid,
                    D_, D_, M_);

            gemm_kernel<128, 64, 16, 8, 4, true, true, false>
                <<<dim3(D_ / 64, CR / 128), 256, 0, stream>>>(
                    hid, w2 + (size_t)l * M_ * D_, b2 + l * D_, x + r0 * D_,
                    M_, M_, D_);
        }
    }
}

// Round 3
// 1516.161 us; speedup vs baseline: 6.8193x; 6.8193x over previous
//
#include <hip/hip_runtime.h>
#include <math.h>

#define L_ 4
#define D_ 256
#define H_ 8
#define INNER_ 2048
#define M_ 1024
#define B_ 8
#define N_ 1024
#define R_ (B_ * N_)          // 8192 rows
#define QS_ 6144              // qkv row stride (3*INNER)

constexpr float EPS_ = 1e-5f;
constexpr float SCALE_ = 0.0625f;  // 256^-0.5

using f16 = _Float16;
typedef _Float16 f16x8 __attribute__((ext_vector_type(8)));
typedef float f32x4 __attribute__((ext_vector_type(4)));

__device__ __forceinline__ float gelu_f(float x) {
    return 0.5f * x * (1.0f + erff(x * 0.70710678118654752f));
}

// ---------------------------------------------------------------------------
// LayerNorm: one block per row of 256, 256 threads; fp32 in, f16 out
// ---------------------------------------------------------------------------
__global__ __launch_bounds__(256)
void ln_kernel(const float* __restrict__ x, const float* __restrict__ g,
               const float* __restrict__ b, f16* __restrict__ out) {
    const int row = blockIdx.x;
    const int t = threadIdx.x;
    const int wave = t >> 6, lane = t & 63;
    __shared__ float red[8];

    const float v = x[(size_t)row * D_ + t];

    float s = v;
    #pragma unroll
    for (int o = 32; o; o >>= 1) s += __shfl_down(s, o);
    if (lane == 0) red[wave] = s;
    __syncthreads();
    const float mean = (red[0] + red[1] + red[2] + red[3]) * (1.0f / 256.0f);

    const float d = v - mean;
    float s2 = d * d;
    #pragma unroll
    for (int o = 32; o; o >>= 1) s2 += __shfl_down(s2, o);
    if (lane == 0) red[4 + wave] = s2;
    __syncthreads();
    const float var = (red[4] + red[5] + red[6] + red[7]) * (1.0f / 256.0f);

    out[(size_t)row * D_ + t] = (f16)(d * rsqrtf(var + EPS_) * g[t] + b[t]);
}

// ---------------------------------------------------------------------------
// Weight transpose+convert: W[K][N] f32 -> Wt[N][K] f16.  64x64 tiles,
// grid (N/64, K/64, L). K,N multiples of 64.
// ---------------------------------------------------------------------------
__global__ __launch_bounds__(256)
void transpose_w(const float* __restrict__ W, f16* __restrict__ Wt, int K, int N) {
    __shared__ float tile[64][68];
    const int n0 = blockIdx.x * 64, k0 = blockIdx.y * 64;
    const float* Wl = W + (size_t)blockIdx.z * K * N;
    f16* Wtl = Wt + (size_t)blockIdx.z * K * N;
    const int t = threadIdx.x;

    #pragma unroll
    for (int j = 0; j < 4; ++j) {
        const int li = t + 256 * j;
        const int r = li >> 4, c4 = (li & 15) * 4;
        const float4 v = *reinterpret_cast<const float4*>(&Wl[(size_t)(k0 + r) * N + n0 + c4]);
        tile[r][c4] = v.x; tile[r][c4 + 1] = v.y; tile[r][c4 + 2] = v.z; tile[r][c4 + 3] = v.w;
    }
    __syncthreads();
    #pragma unroll
    for (int j = 0; j < 2; ++j) {
        const int li = t + 256 * j;
        const int n = li >> 3, c8 = (li & 7) * 8;
        f16 tmp[8];
        #pragma unroll
        for (int e = 0; e < 8; ++e) tmp[e] = (f16)tile[c8 + e][n];
        *reinterpret_cast<uint4*>(&Wtl[(size_t)(n0 + n) * K + k0 + c8]) =
            *reinterpret_cast<const uint4*>(tmp);
    }
}

// ---------------------------------------------------------------------------
// V transpose: qkv V-slot [token][2048] -> Vt [b][2048][1024] (all f16).
// grid (N/64, 2048/64, CB)
// ---------------------------------------------------------------------------
__global__ __launch_bounds__(256)
void transpose_v(const f16* __restrict__ qkv, f16* __restrict__ Vt) {
    __shared__ f16 tile[64][72];
    const int n0 = blockIdx.x * 64;      // token
    const int d0 = blockIdx.y * 64;      // col within 2048
    const int b = blockIdx.z;
    const int t = threadIdx.x;
    const f16* Vg = qkv + (size_t)b * N_ * QS_ + 4096;

    #pragma unroll
    for (int j = 0; j < 2; ++j) {
        const int li = t + 256 * j;
        const int r = li >> 3, c8 = (li & 7) * 8;
        *reinterpret_cast<uint4*>(&tile[r][c8]) =
            *reinterpret_cast<const uint4*>(&Vg[(size_t)(n0 + r) * QS_ + d0 + c8]);
    }
    __syncthreads();
    #pragma unroll
    for (int j = 0; j < 2; ++j) {
        const int li = t + 256 * j;
        const int dr = li >> 3, c8 = (li & 7) * 8;
        f16 tmp[8];
        #pragma unroll
        for (int e = 0; e < 8; ++e) tmp[e] = tile[c8 + e][dr];
        *reinterpret_cast<uint4*>(&Vt[((size_t)b * INNER_ + d0 + dr) * N_ + n0 + c8]) =
            *reinterpret_cast<const uint4*>(tmp);
    }
}

// ---------------------------------------------------------------------------
// f16 MFMA GEMM: C[rows x Nc] = A[rows x K] @ Wt^T  (Wt is [Nc][K], k-contig)
// Block tile (2*WM x 2*WN), BK=64, 256 threads = 4 waves in 2x2.
// LDS tiles in 16B chunks, XOR-swizzled: chunk' = c ^ (row&7)  (8 chunks/row).
// ---------------------------------------------------------------------------
template <int WM, int WN, bool BIAS, bool RES, bool GELU, bool OUTF16>
__global__ __launch_bounds__(256)
void gemm_f16(const f16* __restrict__ A, int lda, const f16* __restrict__ Wt,
              const float* __restrict__ bias, f16* __restrict__ Cf16,
              float* __restrict__ Cf32, int ldc, int K) {
    constexpr int BM = 2 * WM, BN = 2 * WN, MI = WM / 16, NI = WN / 16;
    __shared__ uint4 As[BM * 8];
    __shared__ uint4 Bs[BN * 8];

    const int t = threadIdx.x;
    const int lane = t & 63, w = t >> 6;
    const int wr = w >> 1, wc = w & 1;
    const int row0 = blockIdx.y * BM, col0 = blockIdx.x * BN;
    const int l15 = lane & 15, l4 = lane >> 4;

    f32x4 acc[MI][NI];
    #pragma unroll
    for (int mi = 0; mi < MI; ++mi)
        #pragma unroll
        for (int ni = 0; ni < NI; ++ni) acc[mi][ni] = (f32x4){0.f, 0.f, 0.f, 0.f};

    for (int k0 = 0; k0 < K; k0 += 64) {
        #pragma unroll
        for (int j = 0; j < BM / 32; ++j) {
            const int ci = t + 256 * j, r = ci >> 3, c = ci & 7;
            As[r * 8 + (c ^ (r & 7))] =
                *reinterpret_cast<const uint4*>(&A[(size_t)(row0 + r) * lda + k0 + c * 8]);
        }
        #pragma unroll
        for (int j = 0; j < BN / 32; ++j) {
            const int ci = t + 256 * j, r = ci >> 3, c = ci & 7;
            Bs[r * 8 + (c ^ (r & 7))] =
                *reinterpret_cast<const uint4*>(&Wt[(size_t)(col0 + r) * K + k0 + c * 8]);
        }
        __syncthreads();

        #pragma unroll
        for (int tk = 0; tk < 2; ++tk) {
            f16x8 af[MI], bf[NI];
            #pragma unroll
            for (int mi = 0; mi < MI; ++mi) {
                const int r = wr * WM + mi * 16 + l15;
                af[mi] = *reinterpret_cast<const f16x8*>(&As[r * 8 + ((tk * 4 + l4) ^ (r & 7))]);
            }
            #pragma unroll
            for (int ni = 0; ni < NI; ++ni) {
                const int r = wc * WN + ni * 16 + l15;
                bf[ni] = *reinterpret_cast<const f16x8*>(&Bs[r * 8 + ((tk * 4 + l4) ^ (r & 7))]);
            }
            #pragma unroll
            for (int mi = 0; mi < MI; ++mi)
                #pragma unroll
                for (int ni = 0; ni < NI; ++ni)
                    acc[mi][ni] = __builtin_amdgcn_mfma_f32_16x16x32_f16(
                        af[mi], bf[ni], acc[mi][ni], 0, 0, 0);
        }
        __syncthreads();
    }

    #pragma unroll
    for (int mi = 0; mi < MI; ++mi) {
        #pragma unroll
        for (int ni = 0; ni < NI; ++ni) {
            const int col = col0 + wc * WN + ni * 16 + l15;
            float bv = 0.f;
            if constexpr (BIAS) bv = bias[col];
            #pragma unroll
            for (int r = 0; r < 4; ++r) {
                const size_t row = row0 + wr * WM + mi * 16 + l4 * 4 + r;
                float v = acc[mi][ni][r] + bv;
                if constexpr (GELU) v = gelu_f(v);
                if constexpr (OUTF16) {
                    Cf16[row * ldc + col] = (f16)v;
                } else {
                    float* p = &Cf32[row * ldc + col];
                    *p = RES ? (*p + v) : v;
                }
            }
        }
    }
}

// ---------------------------------------------------------------------------
// Flash attention, f16 MFMA, in-place (writes Q slot of qkv).
// 256 threads = 4 waves; wave w owns q rows [w*16, w*16+16); KT=64.
// grid (N/64, CB*H).
// ---------------------------------------------------------------------------
__global__ __launch_bounds__(256)
void attn_f16(f16* __restrict__ qkv, const f16* __restrict__ Vt) {
    __shared__ uint4 Ks[64 * 32];    // kv rows x 32 chunks (256 d)  = 32KB
    __shared__ uint4 Vts[256 * 8];   // d rows x 8 chunks (64 kv)    = 32KB
    __shared__ f16 Ps[64 * 64];      // q x kv                       = 8KB

    const int t = threadIdx.x, lane = t & 63, w = t >> 6;
    const int l15 = lane & 15, l4 = lane >> 4;
    const int bh = blockIdx.y;
    const int b = bh >> 3, hh = bh & 7;
    const int q0 = blockIdx.x * 64;

    f16* Qg = qkv + (size_t)b * N_ * QS_ + hh * 256;
    const f16* Kg = Qg + 2048;
    const f16* Vtg = Vt + ((size_t)b * INNER_ + hh * 256) * N_;

    // stage Q tile into Ks, hoist wave's fragments to registers
    #pragma unroll
    for (int j = 0; j < 8; ++j) {
        const int ci = t + 256 * j, r = ci >> 5, c = ci & 31;
        Ks[r * 32 + (c ^ (r & 7))] =
            *reinterpret_cast<const uint4*>(&Qg[(size_t)(q0 + r) * QS_ + c * 8]);
    }
    __syncthreads();
    f16x8 qf[8];
    {
        const int r = w * 16 + l15;
        #pragma unroll
        for (int tk = 0; tk < 8; ++tk)
            qf[tk] = *reinterpret_cast<const f16x8*>(&Ks[r * 32 + ((tk * 4 + l4) ^ (r & 7))]);
    }
    __syncthreads();

    float m_run[4] = {-INFINITY, -INFINITY, -INFINITY, -INFINITY};
    float l_run[4] = {0.f, 0.f, 0.f, 0.f};
    f32x4 outf[16];
    #pragma unroll
    for (int f = 0; f < 16; ++f) outf[f] = (f32x4){0.f, 0.f, 0.f, 0.f};

    for (int kt = 0; kt < 16; ++kt) {
        const int kv0 = kt * 64;
        #pragma unroll
        for (int j = 0; j < 8; ++j) {
            const int ci = t + 256 * j, r = ci >> 5, c = ci & 31;
            Ks[r * 32 + (c ^ (r & 7))] =
                *reinterpret_cast<const uint4*>(&Kg[(size_t)(kv0 + r) * QS_ + c * 8]);
        }
        #pragma unroll
        for (int j = 0; j < 8; ++j) {
            const int ci = t + 256 * j, r = ci >> 3, c = ci & 7;
            Vts[r * 8 + (c ^ (r & 7))] =
                *reinterpret_cast<const uint4*>(&Vtg[(size_t)r * N_ + kv0 + c * 8]);
        }
        __syncthreads();

        // S = Q @ K^T  (wave: 16 q x 64 kv)
        f32x4 sf[4];
        #pragma unroll
        for (int nf = 0; nf < 4; ++nf) sf[nf] = (f32x4){0.f, 0.f, 0.f, 0.f};
        #pragma unroll
        for (int tk = 0; tk < 8; ++tk) {
            #pragma unroll
            for (int nf = 0; nf < 4; ++nf) {
                const int r = nf * 16 + l15;
                const f16x8 bf =
                    *reinterpret_cast<const f16x8*>(&Ks[r * 32 + ((tk * 4 + l4) ^ (r & 7))]);
                sf[nf] = __builtin_amdgcn_mfma_f32_16x16x32_f16(qf[tk], bf, sf[nf], 0, 0, 0);
            }
        }

        // online softmax over kv (rows: q = w*16 + 4*l4 + r)
        float mx[4], al[4], ps[4], p[4][4];
        #pragma unroll
        for (int r = 0; r < 4; ++r) {
            float v0 = sf[0][r] * SCALE_, v1 = sf[1][r] * SCALE_;
            float v2 = sf[2][r] * SCALE_, v3 = sf[3][r] * SCALE_;
            p[0][r] = v0; p[1][r] = v1; p[2][r] = v2; p[3][r] = v3;
            mx[r] = fmaxf(fmaxf(v0, v1), fmaxf(v2, v3));
        }
        #pragma unroll
        for (int off = 1; off < 16; off <<= 1)
            #pragma unroll
            for (int r = 0; r < 4; ++r) mx[r] = fmaxf(mx[r], __shfl_xor(mx[r], off));
        #pragma unroll
        for (int r = 0; r < 4; ++r) {
            const float nm = fmaxf(m_run[r], mx[r]);
            al[r] = __expf(m_run[r] - nm);
            m_run[r] = nm;
            float sum = 0.f;
            #pragma unroll
            for (int nf = 0; nf < 4; ++nf) {
                p[nf][r] = __expf(p[nf][r] - nm);
                sum += p[nf][r];
            }
            ps[r] = sum;
        }
        #pragma unroll
        for (int off = 1; off < 16; off <<= 1)
            #pragma unroll
            for (int r = 0; r < 4; ++r) ps[r] += __shfl_xor(ps[r], off);
        #pragma unroll
        for (int r = 0; r < 4; ++r) {
            l_run[r] = l_run[r] * al[r] + ps[r];
            const int q = w * 16 + l4 * 4 + r;
            #pragma unroll
            for (int nf = 0; nf < 4; ++nf) {
                const int kv = nf * 16 + l15;
                Ps[q * 64 + (kv ^ ((q & 7) << 3))] = (f16)p[nf][r];
            }
        }
        #pragma unroll
        for (int f = 0; f < 16; ++f)
            #pragma unroll
            for (int r = 0; r < 4; ++r) outf[f][r] *= al[r];
        __syncthreads();

        // PV: out += P @ V   (B-frags from Vt rows, kv-contiguous)
        #pragma unroll
        for (int tk = 0; tk < 2; ++tk) {
            const int rq = w * 16 + l15;
            const int c = tk * 4 + l4;
            const f16x8 pa =
                *reinterpret_cast<const f16x8*>(&Ps[rq * 64 + ((c ^ (rq & 7)) * 8)]);
            #pragma unroll
            for (int f = 0; f < 16; ++f) {
                const int d = f * 16 + l15;
                const f16x8 vf = *reinterpret_cast<const f16x8*>(&Vts[d * 8 + (c ^ (d & 7))]);
                outf[f] = __builtin_amdgcn_mfma_f32_16x16x32_f16(pa, vf, outf[f], 0, 0, 0);
            }
        }
        __syncthreads();
    }

    // normalize, write back to Q slot
    float inv[4];
    #pragma unroll
    for (int r = 0; r < 4; ++r) inv[r] = 1.0f / l_run[r];
    #pragma unroll
    for (int f = 0; f < 16; ++f) {
        const int d = f * 16 + l15;
        #pragma unroll
        for (int r = 0; r < 4; ++r) {
            const int q = w * 16 + l4 * 4 + r;
            Qg[(size_t)(q0 + q) * QS_ + d] = (f16)(outf[f][r] * inv[r]);
        }
    }
}

// ---------------------------------------------------------------------------
extern "C" void kernel_launch(void* const* d_in, const int* in_sizes, int n_in,
                              void* d_out, int out_size, void* d_ws, size_t ws_size,
                              hipStream_t stream) {
    (void)in_sizes; (void)n_in; (void)out_size;

    const float* inputs = (const float*)d_in[0];
    const float* ln1_g  = (const float*)d_in[1];
    const float* ln1_b  = (const float*)d_in[2];
    const float* w_qkv  = (const float*)d_in[3];
    const float* w_proj = (const float*)d_in[4];
    const float* b_proj = (const float*)d_in[5];
    const float* ln2_g  = (const float*)d_in[6];
    const float* ln2_b  = (const float*)d_in[7];
    const float* w1     = (const float*)d_in[8];
    const float* b1     = (const float*)d_in[9];
    const float* w2     = (const float*)d_in[10];
    const float* b2     = (const float*)d_in[11];

    float* x = (float*)d_out;               // running residual [R x D] fp32

    // ws carve-up (all f16)
    f16* ws = (f16*)d_ws;
    const size_t SZ_WQKV = (size_t)L_ * D_ * 3 * INNER_;   // 6.29M
    const size_t SZ_WPRJ = (size_t)L_ * INNER_ * D_;       // 2.10M
    const size_t SZ_W1   = (size_t)L_ * D_ * M_;           // 1.05M
    const size_t SZ_W2   = (size_t)L_ * M_ * D_;           // 1.05M
    const size_t SZ_H    = (size_t)R_ * D_;                // 2.10M
    f16* wt_qkv = ws;
    f16* wt_prj = wt_qkv + SZ_WQKV;
    f16* wt1    = wt_prj + SZ_WPRJ;
    f16* wt2    = wt1 + SZ_W1;
    f16* h      = wt2 + SZ_W2;
    f16* qc     = h + SZ_H;                 // per-chunk qkv [CR x 6144]

    const size_t fixed = SZ_WQKV + SZ_WPRJ + SZ_W1 + SZ_W2 + SZ_H;
    int nch = 1;
    while (nch < 8 &&
           2 * (fixed + ((size_t)R_ / nch) * (QS_ + INNER_)) > ws_size)
        nch *= 2;
    const int CB = B_ / nch;
    const int CR = R_ / nch;
    f16* vt = qc + (size_t)CR * QS_;        // per-chunk Vt [CB x 2048 x 1024]

    hipMemcpyAsync(x, inputs, (size_t)R_ * D_ * sizeof(float),
                   hipMemcpyDeviceToDevice, stream);

    // weight prep (every call; deterministic)
    transpose_w<<<dim3(96, 4, L_), 256, 0, stream>>>(w_qkv, wt_qkv, D_, 3 * INNER_);
    transpose_w<<<dim3(4, 32, L_), 256, 0, stream>>>(w_proj, wt_prj, INNER_, D_);
    transpose_w<<<dim3(16, 4, L_), 256, 0, stream>>>(w1, wt1, D_, M_);
    transpose_w<<<dim3(4, 16, L_), 256, 0, stream>>>(w2, wt2, M_, D_);

    for (int l = 0; l < L_; ++l) {
        ln_kernel<<<R_, 256, 0, stream>>>(x, ln1_g + l * D_, ln1_b + l * D_, h);

        for (int c = 0; c < nch; ++c) {
            const size_t r0 = (size_t)c * CR;
            gemm_f16<64, 64, false, false, false, true>
                <<<dim3(QS_ / 128, CR / 128), 256, 0, stream>>>(
                    h + r0 * D_, D_, wt_qkv + (size_t)l * D_ * 3 * INNER_,
                    nullptr, qc, nullptr, QS_, D_);

            transpose_v<<<dim3(16, 32, CB), 256, 0, stream>>>(qc, vt);

            attn_f16<<<dim3(16, CB * H_), 256, 0, stream>>>(qc, vt);

            gemm_f16<32, 32, true, true, false, false>
                <<<dim3(D_ / 64, CR / 64), 256, 0, stream>>>(
                    qc, QS_, wt_prj + (size_t)l * INNER_ * D_,
                    b_proj + l * D_, nullptr, x + r0 * D_, D_, INNER_);
        }

        ln_kernel<<<R_, 256, 0, stream>>>(x, ln2_g + l * D_, ln2_b + l * D_, h);

        for (int c = 0; c < nch; ++c) {
            const size_t r0 = (size_t)c * CR;
            f16* hid = qc;  // [CR x M] aliases qkv chunk buffer
            gemm_f16<64, 64, true, false, true, true>
                <<<dim3(M_ / 128, CR / 128), 256, 0, stream>>>(
                    h + r0 * D_, D_, wt1 + (size_t)l * D_ * M_,
                    b1 + l * M_, hid, nullptr, M_, D_);

            gemm_f16<32, 32, true, true, false, false>
                <<<dim3(D_ / 64, CR / 64), 256, 0, stream>>>(
                    hid, M_, wt2 + (size_t)l * M_ * D_,
                    b2 + l * D_, nullptr, x + r0 * D_, D_, M_);
        }
    }
}